// Round 18
// baseline (155.508 us; speedup 1.0000x reference)
//
#include <hip/hip_runtime.h>
#include <math.h>

#define NB 4
#define T_SEQ 2048
#define C_DIM 768
#define NH 12
#define HD 64
#define M_TOK (NB * T_SEQ)            // 8192
#define NE ((size_t)M_TOK * C_DIM)    // 6291456
#define WE ((size_t)C_DIM * C_DIM)    // 589824
#define QSCALE 0.18033688011112042f   // 0.125 * log2(e)

typedef short bf16x8 __attribute__((ext_vector_type(8)));
typedef float f32x4 __attribute__((ext_vector_type(4)));
typedef unsigned short u16x4 __attribute__((ext_vector_type(4)));
typedef unsigned short u16x8 __attribute__((ext_vector_type(8)));
typedef unsigned short ushort_t;

__device__ __forceinline__ unsigned short f2bf(float x) {
    unsigned u = __float_as_uint(x);
    u += 0x7FFFu + ((u >> 16) & 1u);
    return (unsigned short)(u >> 16);
}
__device__ __forceinline__ float bf2f(unsigned short h) {
    return __uint_as_float(((unsigned)h) << 16);
}
__device__ __forceinline__ int sw128(int row, int bytecol) {
    return row * 128 + (bytecol ^ ((row & 7) << 4));
}
__device__ __forceinline__ void gload16(const ushort_t* gp, ushort_t* lp) {
    __builtin_amdgcn_global_load_lds(
        (const __attribute__((address_space(1))) unsigned int*)(const void*)gp,
        (__attribute__((address_space(3))) unsigned int*)(void*)lp, 16, 0, 0);
}

// ---------------------------------------------------------------------------
// prep: blocks [0,3072) split X -> single RNE bf16. Blocks [3072,3648):
// transpose-split weights into WT [N][K]; lo half written ONLY for WO
// (the 1-pass QKV GEMM never reads WQ/WK/WV lo).
// ---------------------------------------------------------------------------
__global__ __launch_bounds__(256) void prep(
    const float* __restrict__ X,
    const float* __restrict__ wq, const float* __restrict__ wk,
    const float* __restrict__ wv, const float* __restrict__ wo,
    ushort_t* __restrict__ XH, ushort_t* __restrict__ Wbase)
{
    __shared__ float T[64][65];
    const int tid = threadIdx.x;
    const int bid = blockIdx.x;

    if (bid < 3072) {
        const size_t i = ((size_t)bid * 256 + tid) * 8;
        const float4 f0 = *(const float4*)&X[i];
        const float4 f1 = *(const float4*)&X[i + 4];
        const float xs[8] = {f0.x, f0.y, f0.z, f0.w, f1.x, f1.y, f1.z, f1.w};
        u16x8 h;
        #pragma unroll
        for (int j = 0; j < 8; ++j) h[j] = f2bf(xs[j]);
        *(u16x8*)&XH[i] = h;
        return;
    }

    const int r_ = bid - 3072;
    const int z = r_ / 144;
    const int rem = r_ % 144;
    const int ti = rem / 12, nj = rem % 12;
    const float* W = (z == 0) ? wq : (z == 1) ? wk : (z == 2) ? wv : wo;
    ushort_t* TH = Wbase + (size_t)z * 2 * WE;
    ushort_t* TL = TH + WE;
    {
        const int r = tid >> 2, cq = (tid & 3) * 16;
        #pragma unroll
        for (int j = 0; j < 4; ++j) {
            const float4 f = *(const float4*)&W[(size_t)(ti * 64 + r) * C_DIM + nj * 64 + cq + j * 4];
            T[r][cq + j * 4 + 0] = f.x;
            T[r][cq + j * 4 + 1] = f.y;
            T[r][cq + j * 4 + 2] = f.z;
            T[r][cq + j * 4 + 3] = f.w;
        }
    }
    __syncthreads();
    {
        const int n = tid >> 2, kq = (tid & 3) * 16;
        u16x8 h0, h1, l0, l1;
        #pragma unroll
        for (int j = 0; j < 8; ++j) {
            float v = T[kq + j][n];
            unsigned short hh = f2bf(v);
            h0[j] = hh; l0[j] = f2bf(v - bf2f(hh));
            v = T[kq + 8 + j][n];
            hh = f2bf(v);
            h1[j] = hh; l1[j] = f2bf(v - bf2f(hh));
        }
        const size_t o = (size_t)(nj * 64 + n) * C_DIM + ti * 64 + kq;
        *(u16x8*)&TH[o] = h0; *(u16x8*)&TH[o + 8] = h1;
        if (z == 3) {                      // lo needed only for WO (2-pass out)
            *(u16x8*)&TL[o] = l0; *(u16x8*)&TL[o + 8] = l1;
        }
    }
}

// ---------------------------------------------------------------------------
// Fused QKV GEMM, 1-pass, 128x128 tile, BK=32, double-buffered (r14).
// ---------------------------------------------------------------------------
__global__ __launch_bounds__(256, 4) void gemm_qkv(
    const ushort_t* __restrict__ XH,
    const ushort_t* __restrict__ WQH, const ushort_t* __restrict__ WKH,
    const ushort_t* __restrict__ WVH,
    const float* __restrict__ bq, const float* __restrict__ bk,
    const float* __restrict__ bv,
    ushort_t* __restrict__ Qo, ushort_t* __restrict__ Ko, ushort_t* __restrict__ VTo)
{
    __shared__ ushort_t TA[2][128 * 32];      // 16 KB
    __shared__ ushort_t TB[2][128 * 32];      // 16 KB

    const int tid = threadIdx.x, lane = tid & 63, w = tid >> 6;
    const int l15 = lane & 15, g = lane >> 4;
    const int wr = w >> 1, wc = w & 1;

    int bid = (int)blockIdx.x;
    bid = (bid & 7) * 144 + (bid >> 3);     // 1152 = 8*144, bijective
    const int bm = bid / 18, bn = bid % 18;
    const int wsel = bn / 6, bnw = bn % 6;

    const ushort_t* BH = (wsel == 0) ? WQH : (wsel == 1) ? WKH : WVH;
    const float* bias = (wsel == 0) ? bq : (wsel == 1) ? bk : bv;

    f32x4 acc[4][4];
    #pragma unroll
    for (int m = 0; m < 4; ++m)
        #pragma unroll
        for (int n = 0; n < 4; ++n) acc[m][n] = (f32x4){0.f, 0.f, 0.f, 0.f};

    auto stage = [&](int buf, int k0) {
        #pragma unroll
        for (int p = 0; p < 4; ++p) {
            const int cb = 256 * p + 64 * w;      // wave-uniform chunk base
            const int c  = cb + lane;
            const int row = (c & 511) >> 2;
            const int slot = (c & 3) ^ ((row >> 1) & 3);
            if (cb < 512)
                gload16(XH + ((size_t)bm * 128 + row) * C_DIM + k0 + slot * 8,
                        &TA[buf][(cb & 511) * 8]);
            else
                gload16(BH + ((size_t)bnw * 128 + row) * C_DIM + k0 + slot * 8,
                        &TB[buf][(cb & 511) * 8]);
        }
    };

    stage(0, 0);
    int cur = 0;
    if (wsel < 2) {
        for (int k0 = 0; k0 < C_DIM; k0 += 32) {
            __syncthreads();
            if (k0 + 32 < C_DIM) stage(cur ^ 1, k0 + 32);
            bf16x8 ah[4], bh_[4];
            #pragma unroll
            for (int m = 0; m < 4; ++m) {
                const int r = 64 * wr + 16 * m + l15;
                const int off = r * 64 + ((g ^ ((r >> 1) & 3)) << 4);
                ah[m] = *(const bf16x8*)((const char*)TA[cur] + off);
            }
            #pragma unroll
            for (int n = 0; n < 4; ++n) {
                const int r = 64 * wc + 16 * n + l15;
                const int off = r * 64 + ((g ^ ((r >> 1) & 3)) << 4);
                bh_[n] = *(const bf16x8*)((const char*)TB[cur] + off);
            }
            #pragma unroll
            for (int m = 0; m < 4; ++m)
                #pragma unroll
                for (int n = 0; n < 4; ++n)
                    acc[m][n] = __builtin_amdgcn_mfma_f32_16x16x32_bf16(bh_[n], ah[m], acc[m][n], 0, 0, 0);
            cur ^= 1;
        }
        const float oscale = (wsel == 0) ? QSCALE : 1.0f;
        ushort_t* OH = (wsel == 0) ? Qo : Ko;
        #pragma unroll
        for (int n = 0; n < 4; ++n) {
            const int colw0 = bnw * 128 + 64 * wc + 16 * n + 4 * g;
            const float4 bv4 = *(const float4*)&bias[colw0];
            const float bvr[4] = {bv4.x, bv4.y, bv4.z, bv4.w};
            const int h = colw0 >> 6, d0 = colw0 & 63;
            #pragma unroll
            for (int m = 0; m < 4; ++m) {
                const int t = bm * 128 + 64 * wr + 16 * m + l15;
                const int b = t >> 11, tt = t & (T_SEQ - 1);
                u16x4 ph;
                #pragma unroll
                for (int r = 0; r < 4; ++r)
                    ph[r] = f2bf((acc[m][n][r] + bvr[r]) * oscale);
                *(u16x4*)&OH[(((size_t)b * NH + h) * T_SEQ + tt) * HD + d0] = ph;
            }
        }
    } else {
        for (int k0 = 0; k0 < C_DIM; k0 += 32) {
            __syncthreads();
            if (k0 + 32 < C_DIM) stage(cur ^ 1, k0 + 32);
            bf16x8 ah[4], bh_[4];
            #pragma unroll
            for (int m = 0; m < 4; ++m) {
                const int r = 64 * wr + 16 * m + l15;
                const int off = r * 64 + ((g ^ ((r >> 1) & 3)) << 4);
                ah[m] = *(const bf16x8*)((const char*)TA[cur] + off);
            }
            #pragma unroll
            for (int n = 0; n < 4; ++n) {
                const int r = 64 * wc + 16 * n + l15;
                const int off = r * 64 + ((g ^ ((r >> 1) & 3)) << 4);
                bh_[n] = *(const bf16x8*)((const char*)TB[cur] + off);
            }
            #pragma unroll
            for (int m = 0; m < 4; ++m)
                #pragma unroll
                for (int n = 0; n < 4; ++n)
                    acc[m][n] = __builtin_amdgcn_mfma_f32_16x16x32_bf16(ah[m], bh_[n], acc[m][n], 0, 0, 0);
            cur ^= 1;
        }
        #pragma unroll
        for (int n = 0; n < 4; ++n) {
            const int colw = bnw * 128 + 64 * wc + 16 * n + l15;
            const float bv_ = bias[colw];
            const int h = colw >> 6, d = colw & 63;
            #pragma unroll
            for (int m = 0; m < 4; ++m) {
                const int row0 = bm * 128 + 64 * wr + 16 * m + 4 * g;
                u16x4 ph;
                #pragma unroll
                for (int r = 0; r < 4; ++r) ph[r] = f2bf(acc[m][n][r] + bv_);
                const int b = row0 >> 11, t0 = row0 & (T_SEQ - 1);
                *(u16x4*)&VTo[(((size_t)b * NH + h) * HD + d) * T_SEQ + t0] = ph;
            }
        }
    }
}

// ---------------------------------------------------------------------------
// Output GEMM, 2-pass (a*wh + a*wl), 128x64 tile, double-buffered (r17).
// ---------------------------------------------------------------------------
__global__ __launch_bounds__(256, 4) void gemm_out(
    const ushort_t* __restrict__ AB,
    const ushort_t* __restrict__ BH, const ushort_t* __restrict__ BL,
    const float* __restrict__ bias, float* __restrict__ OutF)
{
    __shared__ ushort_t TA[2][128 * 32];      // 16 KB
    __shared__ ushort_t TB[2][2][64 * 32];    // 16 KB

    const int tid = threadIdx.x, lane = tid & 63, w = tid >> 6;
    const int l15 = lane & 15, g = lane >> 4;
    const int wr = w >> 1, wc = w & 1;

    int bid = (int)blockIdx.x;
    bid = (bid & 7) * 96 + (bid >> 3);     // 768 = 8*96
    const int bm = bid / 12, bn = bid % 12;

    f32x4 acc[4][2];
    #pragma unroll
    for (int m = 0; m < 4; ++m)
        #pragma unroll
        for (int n = 0; n < 2; ++n) acc[m][n] = (f32x4){0.f, 0.f, 0.f, 0.f};

    auto stage = [&](int buf, int k0) {
        #pragma unroll
        for (int p = 0; p < 4; ++p) {
            const int c = w + 4 * p;       // 0..15
            if (c < 8) {
                const int row = c * 16 + (lane >> 2);
                const int slot = (lane & 3) ^ ((row >> 1) & 3);
                gload16(AB + ((size_t)bm * 128 + row) * C_DIM + k0 + slot * 8,
                        &TA[buf][c * 512]);
            } else {
                const int t_ = (c - 8) >> 2;
                const int cc = c & 3;
                const int row = cc * 16 + (lane >> 2);
                const int slot = (lane & 3) ^ ((row >> 1) & 3);
                const ushort_t* src = (t_ ? BL : BH) + ((size_t)bn * 64 + row) * C_DIM + k0 + slot * 8;
                gload16(src, &TB[buf][t_][cc * 512]);
            }
        }
    };

    stage(0, 0);
    int cur = 0;
    for (int k0 = 0; k0 < C_DIM; k0 += 32) {
        __syncthreads();
        if (k0 + 32 < C_DIM) stage(cur ^ 1, k0 + 32);

        bf16x8 a_[4], bh_[2], bl_[2];
        #pragma unroll
        for (int m = 0; m < 4; ++m) {
            const int r = 64 * wr + 16 * m + l15;
            const int off = r * 64 + ((g ^ ((r >> 1) & 3)) << 4);
            a_[m] = *(const bf16x8*)((const char*)TA[cur] + off);
        }
        #pragma unroll
        for (int n = 0; n < 2; ++n) {
            const int r = 32 * wc + 16 * n + l15;
            const int off = r * 64 + ((g ^ ((r >> 1) & 3)) << 4);
            bh_[n] = *(const bf16x8*)((const char*)TB[cur][0] + off);
            bl_[n] = *(const bf16x8*)((const char*)TB[cur][1] + off);
        }
        #pragma unroll
        for (int m = 0; m < 4; ++m)
            #pragma unroll
            for (int n = 0; n < 2; ++n) {
                acc[m][n] = __builtin_amdgcn_mfma_f32_16x16x32_bf16(a_[m], bh_[n], acc[m][n], 0, 0, 0);
                acc[m][n] = __builtin_amdgcn_mfma_f32_16x16x32_bf16(a_[m], bl_[n], acc[m][n], 0, 0, 0);
            }
        cur ^= 1;
    }

    #pragma unroll
    for (int n = 0; n < 2; ++n) {
        const int col = bn * 64 + 32 * wc + 16 * n + l15;
        const float bv = bias[col];
        #pragma unroll
        for (int m = 0; m < 4; ++m) {
            const int row0 = bm * 128 + 64 * wr + 16 * m + 4 * g;
            #pragma unroll
            for (int r = 0; r < 4; ++r)
                OutF[(size_t)(row0 + r) * C_DIM + col] = acc[m][n][r] + bv;
        }
    }
}

// ---------------------------------------------------------------------------
// Flash attention v10: 128 threads / 2 waves, 64 q-rows per block (32/wave,
// reg-blocked as v7). Grid 1536 = 6 blocks/CU x 2 waves = same 12 waves/CU
// as v9 but 6 INDEPENDENT barrier domains (half-size barriers, more overlap).
// KVBLK=64, LDS 24 KB. Per-row math identical to v7/v9 -> same output.
// ---------------------------------------------------------------------------
__global__ __launch_bounds__(128, 3) void attn_fuse10(
    const ushort_t* __restrict__ QB, const ushort_t* __restrict__ KB,
    const ushort_t* __restrict__ VTB, ushort_t* __restrict__ ABo)
{
    __shared__ ushort_t Ks[64 * 64];      // 8 KB
    __shared__ ushort_t Vt[64 * 64];      // 8 KB
    __shared__ ushort_t Pm[2][32 * 64];   // 8 KB

    const int tid = threadIdx.x, lane = tid & 63, w = tid >> 6;   // w = 0..1
    const int l15 = lane & 15, g = lane >> 4;

    int bid = (int)blockIdx.x;
    bid = (bid & 7) * 192 + (bid >> 3);   // 1536 = 8*192, bijective
    const int bh = bid >> 5, qt = bid & 31;
    const int b = bh / NH, h = bh % NH;

    bf16x8 qf0[2], qf1[2];
    #pragma unroll
    for (int kc = 0; kc < 2; ++kc) {
        const size_t base = ((size_t)bh * T_SEQ + qt * 64 + 32 * w + l15) * HD + kc * 32 + g * 8;
        qf0[kc] = *(const bf16x8*)&QB[base];
        qf1[kc] = *(const bf16x8*)&QB[base + (size_t)16 * HD];
    }

    bf16x8 onesf;
    #pragma unroll
    for (int j = 0; j < 8; ++j) onesf[j] = (short)0x3F80;

    f32x4 o0[4], o1[4];
    #pragma unroll
    for (int nd = 0; nd < 4; ++nd) {
        o0[nd] = (f32x4){0.f, 0.f, 0.f, 0.f};
        o1[nd] = (f32x4){0.f, 0.f, 0.f, 0.f};
    }
    f32x4 ol0 = (f32x4){0.f, 0.f, 0.f, 0.f};
    f32x4 ol1 = (f32x4){0.f, 0.f, 0.f, 0.f};

    const ushort_t* kb = KB + (size_t)bh * T_SEQ * HD;
    const ushort_t* vb = VTB + (size_t)bh * HD * T_SEQ;
    const int swz = (l15 & 7) << 4;

    // staging: 512 K-chunks + 512 V-chunks of 16B per 64-key tile; thread
    // covers chunks {64w + lane + 128i, i=0..3} of each. LDS dest is
    // wave-uniform base (+lane*16B implicit); source col pre-swizzled.
    const ushort_t *gK[4], *gV[4];
    #pragma unroll
    for (int i = 0; i < 4; ++i) {
        const int c = 64 * w + lane + 128 * i;
        const int row = c >> 3;
        const int colb = ((c & 7) * 16) ^ ((row & 7) << 4);
        gK[i] = kb + (size_t)row * HD + (colb >> 1);
        gV[i] = vb + (size_t)row * T_SEQ + (colb >> 1);
    }

    for (int kt = 0; kt < T_SEQ; kt += 64) {
        __syncthreads();                 // previous tile's reads complete
        #pragma unroll
        for (int i = 0; i < 4; ++i) {
            const int cb = 64 * w + 128 * i;     // wave-uniform chunk base
            gload16(gK[i], &Ks[cb * 8]); gK[i] += (size_t)64 * HD;
            gload16(gV[i], &Vt[cb * 8]); gV[i] += 64;
        }
        __syncthreads();                 // tile staged (DMA drained by barrier)

        // ---- QK^T (swapped): each kf feeds both q-halves
        f32x4 s0[4], s1[4];
        #pragma unroll
        for (int nb = 0; nb < 4; ++nb) {
            s0[nb] = (f32x4){0.f, 0.f, 0.f, 0.f};
            s1[nb] = (f32x4){0.f, 0.f, 0.f, 0.f};
        }
        __builtin_amdgcn_s_setprio(1);
        #pragma unroll
        for (int kc = 0; kc < 2; ++kc)
            #pragma unroll
            for (int nb = 0; nb < 4; ++nb) {
                const bf16x8 kf = *(const bf16x8*)((const char*)Ks + sw128(16 * nb + l15, kc * 64 + g * 16));
                s0[nb] = __builtin_amdgcn_mfma_f32_16x16x32_bf16(kf, qf0[kc], s0[nb], 0, 0, 0);
                s1[nb] = __builtin_amdgcn_mfma_f32_16x16x32_bf16(kf, qf1[kc], s1[nb], 0, 0, 0);
            }
        __builtin_amdgcn_s_setprio(0);

        // ---- no-max softmax: p = exp2(s) (raw v_exp_f32); truncate-pack
        #pragma unroll
        for (int nb = 0; nb < 4; ++nb) {
            const float a0 = __builtin_amdgcn_exp2f(s0[nb][0]);
            const float a1 = __builtin_amdgcn_exp2f(s0[nb][1]);
            const float a2 = __builtin_amdgcn_exp2f(s0[nb][2]);
            const float a3 = __builtin_amdgcn_exp2f(s0[nb][3]);
            const unsigned dwa0 = __builtin_amdgcn_perm(
                __float_as_uint(a1), __float_as_uint(a0), 0x07060302u);
            const unsigned dwa1 = __builtin_amdgcn_perm(
                __float_as_uint(a3), __float_as_uint(a2), 0x07060302u);
            *(uint2*)((char*)Pm[w] + l15 * 128 + ((32 * nb + 8 * g) ^ swz)) =
                make_uint2(dwa0, dwa1);

            const float b0 = __builtin_amdgcn_exp2f(s1[nb][0]);
            const float b1 = __builtin_amdgcn_exp2f(s1[nb][1]);
            const float b2 = __builtin_amdgcn_exp2f(s1[nb][2]);
            const float b3 = __builtin_amdgcn_exp2f(s1[nb][3]);
            const unsigned dwb0 = __builtin_amdgcn_perm(
                __float_as_uint(b1), __float_as_uint(b0), 0x07060302u);
            const unsigned dwb1 = __builtin_amdgcn_perm(
                __float_as_uint(b3), __float_as_uint(b2), 0x07060302u);
            *(uint2*)((char*)Pm[w] + (16 + l15) * 128 + ((32 * nb + 8 * g) ^ swz)) =
                make_uint2(dwb0, dwb1);
        }

        // ---- PV (swapped) + l via ones-MFMA; single setprio window
        __builtin_amdgcn_s_setprio(1);
        #pragma unroll
        for (int kc2 = 0; kc2 < 2; ++kc2) {
            const bf16x8 pb0 = *(const bf16x8*)((const char*)Pm[w] + l15 * 128 + ((kc2 * 64 + g * 16) ^ swz));
            const bf16x8 pb1 = *(const bf16x8*)((const char*)Pm[w] + (16 + l15) * 128 + ((kc2 * 64 + g * 16) ^ swz));
            #pragma unroll
            for (int nd = 0; nd < 4; ++nd) {
                const bf16x8 vf = *(const bf16x8*)((const char*)Vt + sw128(16 * nd + l15, kc2 * 64 + g * 16));
                o0[nd] = __builtin_amdgcn_mfma_f32_16x16x32_bf16(vf, pb0, o0[nd], 0, 0, 0);
                o1[nd] = __builtin_amdgcn_mfma_f32_16x16x32_bf16(vf, pb1, o1[nd], 0, 0, 0);
            }
            ol0 = __builtin_amdgcn_mfma_f32_16x16x32_bf16(onesf, pb0, ol0, 0, 0, 0);
            ol1 = __builtin_amdgcn_mfma_f32_16x16x32_bf16(onesf, pb1, ol1, 0, 0, 0);
        }
        __builtin_amdgcn_s_setprio(0);
    }

    const float inv0 = 1.0f / ol0[0];
    const float inv1 = 1.0f / ol1[0];
    const int t0 = qt * 64 + 32 * w + l15;
    #pragma unroll
    for (int nd = 0; nd < 4; ++nd) {
        u16x4 h0_, h1_;
        #pragma unroll
        for (int r = 0; r < 4; ++r) {
            h0_[r] = f2bf(o0[nd][r] * inv0);
            h1_[r] = f2bf(o1[nd][r] * inv1);
        }
        const size_t col = h * HD + 16 * nd + 4 * g;
        *(u16x4*)&ABo[((size_t)b * T_SEQ + t0) * C_DIM + col] = h0_;
        *(u16x4*)&ABo[((size_t)b * T_SEQ + t0 + 16) * C_DIM + col] = h1_;
    }
}

// ---------------------------------------------------------------------------
extern "C" void kernel_launch(void* const* d_in, const int* in_sizes, int n_in,
                              void* d_out, int out_size, void* d_ws, size_t ws_size,
                              hipStream_t stream)
{
    const float* x  = (const float*)d_in[0];
    const float* wq = (const float*)d_in[1];
    const float* bq = (const float*)d_in[2];
    const float* wk = (const float*)d_in[3];
    const float* bk = (const float*)d_in[4];
    const float* wv = (const float*)d_in[5];
    const float* bv = (const float*)d_in[6];
    const float* wo = (const float*)d_in[7];
    const float* bo = (const float*)d_in[8];

    ushort_t* Wbase = (ushort_t*)d_ws;
    ushort_t* WQ_H = Wbase;
    ushort_t* WK_H = Wbase + 2 * WE;
    ushort_t* WV_H = Wbase + 4 * WE;
    ushort_t* WO_H = Wbase + 6 * WE;
    ushort_t* WO_L = WO_H + WE;
    ushort_t* X_H  = Wbase + 8 * WE;
    ushort_t* K_B  = X_H + 2 * NE;
    ushort_t* VT_B = K_B + NE;
    ushort_t* Q_B = (ushort_t*)d_out;       // consumed before final GEMM writes
    ushort_t* A_B = X_H;                    // aliases X (dead after QKV GEMM)

    const dim3 blk(256);

    prep<<<3648, blk, 0, stream>>>(x, wq, wk, wv, wo, X_H, Wbase);

    gemm_qkv<<<1152, blk, 0, stream>>>(X_H, WQ_H, WK_H, WV_H,
                                       bq, bk, bv, Q_B, K_B, VT_B);

    attn_fuse10<<<1536, dim3(128), 0, stream>>>(Q_B, K_B, VT_B, A_B);

    gemm_out<<<768, blk, 0, stream>>>(A_B, WO_H, WO_L, bo, (float*)d_out);
}

// Round 19
// 150.110 us; speedup vs baseline: 1.0360x; 1.0360x over previous
//
#include <hip/hip_runtime.h>
#include <math.h>

#define NB 4
#define T_SEQ 2048
#define C_DIM 768
#define NH 12
#define HD 64
#define M_TOK (NB * T_SEQ)            // 8192
#define NE ((size_t)M_TOK * C_DIM)    // 6291456
#define WE ((size_t)C_DIM * C_DIM)    // 589824
#define QSCALE 0.18033688011112042f   // 0.125 * log2(e)

typedef short bf16x8 __attribute__((ext_vector_type(8)));
typedef float f32x4 __attribute__((ext_vector_type(4)));
typedef float f32x16 __attribute__((ext_vector_type(16)));
typedef unsigned u32x2 __attribute__((ext_vector_type(2)));
typedef unsigned short u16x4 __attribute__((ext_vector_type(4)));
typedef unsigned short u16x8 __attribute__((ext_vector_type(8)));
typedef unsigned short ushort_t;

__device__ __forceinline__ unsigned short f2bf(float x) {
    unsigned u = __float_as_uint(x);
    u += 0x7FFFu + ((u >> 16) & 1u);
    return (unsigned short)(u >> 16);
}
__device__ __forceinline__ float bf2f(unsigned short h) {
    return __uint_as_float(((unsigned)h) << 16);
}
__device__ __forceinline__ int sw128(int row, int bytecol) {
    return row * 128 + (bytecol ^ ((row & 7) << 4));
}
__device__ __forceinline__ void gload16(const ushort_t* gp, ushort_t* lp) {
    __builtin_amdgcn_global_load_lds(
        (const __attribute__((address_space(1))) unsigned int*)(const void*)gp,
        (__attribute__((address_space(3))) unsigned int*)(void*)lp, 16, 0, 0);
}
// pack two fp32 -> one dword of truncated bf16 (elem0 = lo, elem1 = hi)
__device__ __forceinline__ unsigned pkbf(float hi, float lo) {
    return __builtin_amdgcn_perm(__float_as_uint(hi), __float_as_uint(lo), 0x07060302u);
}

// ---------------------------------------------------------------------------
// prep: blocks [0,3072) split X -> single RNE bf16. Blocks [3072,3648):
// transpose-split weights into WT [N][K]; lo half written only for WO.
// ---------------------------------------------------------------------------
__global__ __launch_bounds__(256) void prep(
    const float* __restrict__ X,
    const float* __restrict__ wq, const float* __restrict__ wk,
    const float* __restrict__ wv, const float* __restrict__ wo,
    ushort_t* __restrict__ XH, ushort_t* __restrict__ Wbase)
{
    __shared__ float T[64][65];
    const int tid = threadIdx.x;
    const int bid = blockIdx.x;

    if (bid < 3072) {
        const size_t i = ((size_t)bid * 256 + tid) * 8;
        const float4 f0 = *(const float4*)&X[i];
        const float4 f1 = *(const float4*)&X[i + 4];
        const float xs[8] = {f0.x, f0.y, f0.z, f0.w, f1.x, f1.y, f1.z, f1.w};
        u16x8 h;
        #pragma unroll
        for (int j = 0; j < 8; ++j) h[j] = f2bf(xs[j]);
        *(u16x8*)&XH[i] = h;
        return;
    }

    const int r_ = bid - 3072;
    const int z = r_ / 144;
    const int rem = r_ % 144;
    const int ti = rem / 12, nj = rem % 12;
    const float* W = (z == 0) ? wq : (z == 1) ? wk : (z == 2) ? wv : wo;
    ushort_t* TH = Wbase + (size_t)z * 2 * WE;
    ushort_t* TL = TH + WE;
    {
        const int r = tid >> 2, cq = (tid & 3) * 16;
        #pragma unroll
        for (int j = 0; j < 4; ++j) {
            const float4 f = *(const float4*)&W[(size_t)(ti * 64 + r) * C_DIM + nj * 64 + cq + j * 4];
            T[r][cq + j * 4 + 0] = f.x;
            T[r][cq + j * 4 + 1] = f.y;
            T[r][cq + j * 4 + 2] = f.z;
            T[r][cq + j * 4 + 3] = f.w;
        }
    }
    __syncthreads();
    {
        const int n = tid >> 2, kq = (tid & 3) * 16;
        u16x8 h0, h1, l0, l1;
        #pragma unroll
        for (int j = 0; j < 8; ++j) {
            float v = T[kq + j][n];
            unsigned short hh = f2bf(v);
            h0[j] = hh; l0[j] = f2bf(v - bf2f(hh));
            v = T[kq + 8 + j][n];
            hh = f2bf(v);
            h1[j] = hh; l1[j] = f2bf(v - bf2f(hh));
        }
        const size_t o = (size_t)(nj * 64 + n) * C_DIM + ti * 64 + kq;
        *(u16x8*)&TH[o] = h0; *(u16x8*)&TH[o + 8] = h1;
        if (z == 3) {
            *(u16x8*)&TL[o] = l0; *(u16x8*)&TL[o + 8] = l1;
        }
    }
}

// ---------------------------------------------------------------------------
// Fused QKV GEMM, 1-pass, 128x128 tile, BK=32, double-buffered (r14/r17).
// ---------------------------------------------------------------------------
__global__ __launch_bounds__(256, 4) void gemm_qkv(
    const ushort_t* __restrict__ XH,
    const ushort_t* __restrict__ WQH, const ushort_t* __restrict__ WKH,
    const ushort_t* __restrict__ WVH,
    const float* __restrict__ bq, const float* __restrict__ bk,
    const float* __restrict__ bv,
    ushort_t* __restrict__ Qo, ushort_t* __restrict__ Ko, ushort_t* __restrict__ VTo)
{
    __shared__ ushort_t TA[2][128 * 32];      // 16 KB
    __shared__ ushort_t TB[2][128 * 32];      // 16 KB

    const int tid = threadIdx.x, lane = tid & 63, w = tid >> 6;
    const int l15 = lane & 15, g = lane >> 4;
    const int wr = w >> 1, wc = w & 1;

    int bid = (int)blockIdx.x;
    bid = (bid & 7) * 144 + (bid >> 3);     // 1152 = 8*144, bijective
    const int bm = bid / 18, bn = bid % 18;
    const int wsel = bn / 6, bnw = bn % 6;

    const ushort_t* BH = (wsel == 0) ? WQH : (wsel == 1) ? WKH : WVH;
    const float* bias = (wsel == 0) ? bq : (wsel == 1) ? bk : bv;

    f32x4 acc[4][4];
    #pragma unroll
    for (int m = 0; m < 4; ++m)
        #pragma unroll
        for (int n = 0; n < 4; ++n) acc[m][n] = (f32x4){0.f, 0.f, 0.f, 0.f};

    auto stage = [&](int buf, int k0) {
        #pragma unroll
        for (int p = 0; p < 4; ++p) {
            const int cb = 256 * p + 64 * w;      // wave-uniform chunk base
            const int c  = cb + lane;
            const int row = (c & 511) >> 2;
            const int slot = (c & 3) ^ ((row >> 1) & 3);
            if (cb < 512)
                gload16(XH + ((size_t)bm * 128 + row) * C_DIM + k0 + slot * 8,
                        &TA[buf][(cb & 511) * 8]);
            else
                gload16(BH + ((size_t)bnw * 128 + row) * C_DIM + k0 + slot * 8,
                        &TB[buf][(cb & 511) * 8]);
        }
    };

    stage(0, 0);
    int cur = 0;
    if (wsel < 2) {
        for (int k0 = 0; k0 < C_DIM; k0 += 32) {
            __syncthreads();
            if (k0 + 32 < C_DIM) stage(cur ^ 1, k0 + 32);
            bf16x8 ah[4], bh_[4];
            #pragma unroll
            for (int m = 0; m < 4; ++m) {
                const int r = 64 * wr + 16 * m + l15;
                const int off = r * 64 + ((g ^ ((r >> 1) & 3)) << 4);
                ah[m] = *(const bf16x8*)((const char*)TA[cur] + off);
            }
            #pragma unroll
            for (int n = 0; n < 4; ++n) {
                const int r = 64 * wc + 16 * n + l15;
                const int off = r * 64 + ((g ^ ((r >> 1) & 3)) << 4);
                bh_[n] = *(const bf16x8*)((const char*)TB[cur] + off);
            }
            #pragma unroll
            for (int m = 0; m < 4; ++m)
                #pragma unroll
                for (int n = 0; n < 4; ++n)
                    acc[m][n] = __builtin_amdgcn_mfma_f32_16x16x32_bf16(bh_[n], ah[m], acc[m][n], 0, 0, 0);
            cur ^= 1;
        }
        const float oscale = (wsel == 0) ? QSCALE : 1.0f;
        ushort_t* OH = (wsel == 0) ? Qo : Ko;
        #pragma unroll
        for (int n = 0; n < 4; ++n) {
            const int colw0 = bnw * 128 + 64 * wc + 16 * n + 4 * g;
            const float4 bv4 = *(const float4*)&bias[colw0];
            const float bvr[4] = {bv4.x, bv4.y, bv4.z, bv4.w};
            const int h = colw0 >> 6, d0 = colw0 & 63;
            #pragma unroll
            for (int m = 0; m < 4; ++m) {
                const int t = bm * 128 + 64 * wr + 16 * m + l15;
                const int b = t >> 11, tt = t & (T_SEQ - 1);
                u16x4 ph;
                #pragma unroll
                for (int r = 0; r < 4; ++r)
                    ph[r] = f2bf((acc[m][n][r] + bvr[r]) * oscale);
                *(u16x4*)&OH[(((size_t)b * NH + h) * T_SEQ + tt) * HD + d0] = ph;
            }
        }
    } else {
        for (int k0 = 0; k0 < C_DIM; k0 += 32) {
            __syncthreads();
            if (k0 + 32 < C_DIM) stage(cur ^ 1, k0 + 32);
            bf16x8 ah[4], bh_[4];
            #pragma unroll
            for (int m = 0; m < 4; ++m) {
                const int r = 64 * wr + 16 * m + l15;
                const int off = r * 64 + ((g ^ ((r >> 1) & 3)) << 4);
                ah[m] = *(const bf16x8*)((const char*)TA[cur] + off);
            }
            #pragma unroll
            for (int n = 0; n < 4; ++n) {
                const int r = 64 * wc + 16 * n + l15;
                const int off = r * 64 + ((g ^ ((r >> 1) & 3)) << 4);
                bh_[n] = *(const bf16x8*)((const char*)TB[cur] + off);
            }
            #pragma unroll
            for (int m = 0; m < 4; ++m)
                #pragma unroll
                for (int n = 0; n < 4; ++n)
                    acc[m][n] = __builtin_amdgcn_mfma_f32_16x16x32_bf16(ah[m], bh_[n], acc[m][n], 0, 0, 0);
            cur ^= 1;
        }
        #pragma unroll
        for (int n = 0; n < 4; ++n) {
            const int colw = bnw * 128 + 64 * wc + 16 * n + l15;
            const float bv_ = bias[colw];
            const int h = colw >> 6, d = colw & 63;
            #pragma unroll
            for (int m = 0; m < 4; ++m) {
                const int row0 = bm * 128 + 64 * wr + 16 * m + 4 * g;
                u16x4 ph;
                #pragma unroll
                for (int r = 0; r < 4; ++r) ph[r] = f2bf(acc[m][n][r] + bv_);
                const int b = row0 >> 11, t0 = row0 & (T_SEQ - 1);
                *(u16x4*)&VTo[(((size_t)b * NH + h) * HD + d) * T_SEQ + t0] = ph;
            }
        }
    }
}

// ---------------------------------------------------------------------------
// Output GEMM, 2-pass (a*wh + a*wl), 128x64 tile, double-buffered (r17).
// ---------------------------------------------------------------------------
__global__ __launch_bounds__(256, 4) void gemm_out(
    const ushort_t* __restrict__ AB,
    const ushort_t* __restrict__ BH, const ushort_t* __restrict__ BL,
    const float* __restrict__ bias, float* __restrict__ OutF)
{
    __shared__ ushort_t TA[2][128 * 32];      // 16 KB
    __shared__ ushort_t TB[2][2][64 * 32];    // 16 KB

    const int tid = threadIdx.x, lane = tid & 63, w = tid >> 6;
    const int l15 = lane & 15, g = lane >> 4;
    const int wr = w >> 1, wc = w & 1;

    int bid = (int)blockIdx.x;
    bid = (bid & 7) * 96 + (bid >> 3);     // 768 = 8*96
    const int bm = bid / 12, bn = bid % 12;

    f32x4 acc[4][2];
    #pragma unroll
    for (int m = 0; m < 4; ++m)
        #pragma unroll
        for (int n = 0; n < 2; ++n) acc[m][n] = (f32x4){0.f, 0.f, 0.f, 0.f};

    auto stage = [&](int buf, int k0) {
        #pragma unroll
        for (int p = 0; p < 4; ++p) {
            const int c = w + 4 * p;       // 0..15
            if (c < 8) {
                const int row = c * 16 + (lane >> 2);
                const int slot = (lane & 3) ^ ((row >> 1) & 3);
                gload16(AB + ((size_t)bm * 128 + row) * C_DIM + k0 + slot * 8,
                        &TA[buf][c * 512]);
            } else {
                const int t_ = (c - 8) >> 2;
                const int cc = c & 3;
                const int row = cc * 16 + (lane >> 2);
                const int slot = (lane & 3) ^ ((row >> 1) & 3);
                const ushort_t* src = (t_ ? BL : BH) + ((size_t)bn * 64 + row) * C_DIM + k0 + slot * 8;
                gload16(src, &TB[buf][t_][cc * 512]);
            }
        }
    };

    stage(0, 0);
    int cur = 0;
    for (int k0 = 0; k0 < C_DIM; k0 += 32) {
        __syncthreads();
        if (k0 + 32 < C_DIM) stage(cur ^ 1, k0 + 32);

        bf16x8 a_[4], bh_[2], bl_[2];
        #pragma unroll
        for (int m = 0; m < 4; ++m) {
            const int r = 64 * wr + 16 * m + l15;
            const int off = r * 64 + ((g ^ ((r >> 1) & 3)) << 4);
            a_[m] = *(const bf16x8*)((const char*)TA[cur] + off);
        }
        #pragma unroll
        for (int n = 0; n < 2; ++n) {
            const int r = 32 * wc + 16 * n + l15;
            const int off = r * 64 + ((g ^ ((r >> 1) & 3)) << 4);
            bh_[n] = *(const bf16x8*)((const char*)TB[cur][0] + off);
            bl_[n] = *(const bf16x8*)((const char*)TB[cur][1] + off);
        }
        #pragma unroll
        for (int m = 0; m < 4; ++m)
            #pragma unroll
            for (int n = 0; n < 2; ++n) {
                acc[m][n] = __builtin_amdgcn_mfma_f32_16x16x32_bf16(a_[m], bh_[n], acc[m][n], 0, 0, 0);
                acc[m][n] = __builtin_amdgcn_mfma_f32_16x16x32_bf16(a_[m], bl_[n], acc[m][n], 0, 0, 0);
            }
        cur ^= 1;
    }

    #pragma unroll
    for (int n = 0; n < 2; ++n) {
        const int col = bn * 64 + 32 * wc + 16 * n + l15;
        const float bv = bias[col];
        #pragma unroll
        for (int m = 0; m < 4; ++m) {
            const int row0 = bm * 128 + 64 * wr + 16 * m + 4 * g;
            #pragma unroll
            for (int r = 0; r < 4; ++r)
                OutF[(size_t)(row0 + r) * C_DIM + col] = acc[m][n][r] + bv;
        }
    }
}

// ---------------------------------------------------------------------------
// Flash attention v11: 32x32x16 MFMA + in-register P via permlane32_swap.
// 4 waves x 32 q, KVBLK=128 (two 64-key halves). P NEVER touches LDS:
// after swapped QK^T (D col = q), truncate-pack p-pairs to bf16 dwords and
// build PV B-fragments with permlane32_swap (lane<->lane+32 exchange, VALU).
// LDS traffic/wave-tile: 16 KB (K+V frags) vs 24 KB before. l via ones-MFMA.
// ---------------------------------------------------------------------------
__global__ __launch_bounds__(256, 3) void attn_fuse11(
    const ushort_t* __restrict__ QB, const ushort_t* __restrict__ KB,
    const ushort_t* __restrict__ VTB, ushort_t* __restrict__ ABo)
{
    __shared__ ushort_t Ks[2][64 * 64];   // [half][key][d] swizzled, 16 KB
    __shared__ ushort_t Vt[2][64 * 64];   // [half][d][key] swizzled, 16 KB

    const int tid = threadIdx.x, lane = tid & 63, w = tid >> 6;
    const int l31 = lane & 31, hl = lane >> 5;   // hl = half-wave index

    int bid = (int)blockIdx.x;
    bid = (bid & 7) * 96 + (bid >> 3);    // 768 = 8*96, bijective
    const int bh = bid >> 4, qt = bid & 15;
    const int b = bh / NH, hed = bh % NH;

    // Q fragments (B-operand of 32x32x16: col = q = l31, k = 8*hl + j)
    bf16x8 qf[4];
    const size_t qrow = (size_t)bh * T_SEQ + qt * 128 + 32 * w + l31;
    #pragma unroll
    for (int ks = 0; ks < 4; ++ks)
        qf[ks] = *(const bf16x8*)&QB[qrow * HD + ks * 16 + 8 * hl];

    bf16x8 onesf;
    #pragma unroll
    for (int j = 0; j < 8; ++j) onesf[j] = (short)0x3F80;   // bf16 1.0

    f32x16 oA = (f32x16)(0.f), oB = (f32x16)(0.f), ol = (f32x16)(0.f);

    const ushort_t* kb = KB + (size_t)bh * T_SEQ * HD;
    const ushort_t* vb = VTB + (size_t)bh * HD * T_SEQ;

    // staging identical to r17 (layouts unchanged)
    const ushort_t *gK0, *gK1, *gV0, *gV1;
    {
        const int c0 = w * 64 + lane;
        const int r0 = c0 >> 3;
        const int cb0 = ((c0 & 7) * 16) ^ ((r0 & 7) << 4);
        gK0 = kb + (size_t)r0 * HD + (cb0 >> 1);
        gV0 = vb + (size_t)r0 * T_SEQ + (cb0 >> 1);
        const int c1 = c0 + 256;
        const int r1 = c1 >> 3;
        const int cb1 = ((c1 & 7) * 16) ^ ((r1 & 7) << 4);
        gK1 = kb + (size_t)r1 * HD + (cb1 >> 1);
        gV1 = vb + (size_t)r1 * T_SEQ + (cb1 >> 1);
    }
    ushort_t* dK0 = &Ks[0][w * 512];
    ushort_t* dK1 = &Ks[0][2048 + w * 512];
    ushort_t* dV0 = &Vt[0][w * 512];
    ushort_t* dV1 = &Vt[0][2048 + w * 512];

    // build one PV B-fragment (16 keys) from 8 p-regs via permlane32_swap
    auto mkfrag = [&](const f32x16& s, int base) -> bf16x8 {
        const unsigned D0 = pkbf(__builtin_amdgcn_exp2f(s[base + 1]),
                                 __builtin_amdgcn_exp2f(s[base + 0]));
        const unsigned D1 = pkbf(__builtin_amdgcn_exp2f(s[base + 3]),
                                 __builtin_amdgcn_exp2f(s[base + 2]));
        const unsigned D2 = pkbf(__builtin_amdgcn_exp2f(s[base + 5]),
                                 __builtin_amdgcn_exp2f(s[base + 4]));
        const unsigned D3 = pkbf(__builtin_amdgcn_exp2f(s[base + 7]),
                                 __builtin_amdgcn_exp2f(s[base + 6]));
        const u32x2 r02 = __builtin_amdgcn_permlane32_swap(D0, D2, false, false);
        const u32x2 r13 = __builtin_amdgcn_permlane32_swap(D1, D3, false, false);
        union { unsigned u[4]; bf16x8 v; } cv;
        cv.u[0] = r02[0]; cv.u[1] = r13[0]; cv.u[2] = r02[1]; cv.u[3] = r13[1];
        return cv.v;
    };

    for (int kt = 0; kt < T_SEQ; kt += 128) {
        __syncthreads();                 // previous tile's reads complete
        gload16(gK0, dK0);
        gload16(gK1, dK1);
        gload16(gV0, dV0);
        gload16(gV1, dV1);
        gload16(gK0 + (size_t)64 * HD, dK0 + 4096);
        gload16(gK1 + (size_t)64 * HD, dK1 + 4096);
        gload16(gV0 + 64, dV0 + 4096);
        gload16(gV1 + 64, dV1 + 4096);
        gK0 += (size_t)128 * HD; gK1 += (size_t)128 * HD;
        gV0 += 128; gV1 += 128;
        __syncthreads();                 // 128-key tile staged

        #pragma unroll
        for (int half = 0; half < 2; ++half) {
            const char* ksb = (const char*)Ks[half];
            const char* vtb = (const char*)Vt[half];

            // ---- QK^T (swapped): D[key][q]; A = K-frag, B = Q-frag
            f32x16 sA = (f32x16)(0.f), sB = (f32x16)(0.f);
            __builtin_amdgcn_s_setprio(1);
            #pragma unroll
            for (int ks = 0; ks < 4; ++ks) {
                const int bc = ks * 32 + 16 * hl;
                const bf16x8 kfA = *(const bf16x8*)(ksb + sw128(l31, bc));
                const bf16x8 kfB = *(const bf16x8*)(ksb + sw128(32 + l31, bc));
                sA = __builtin_amdgcn_mfma_f32_32x32x16_bf16(kfA, qf[ks], sA, 0, 0, 0);
                sB = __builtin_amdgcn_mfma_f32_32x32x16_bf16(kfB, qf[ks], sB, 0, 0, 0);
            }
            __builtin_amdgcn_s_setprio(0);

            // ---- no-max softmax + in-register P fragments (no LDS)
            bf16x8 pb0 = mkfrag(sA, 0);
            bf16x8 pb1 = mkfrag(sA, 8);
            bf16x8 pb2 = mkfrag(sB, 0);
            bf16x8 pb3 = mkfrag(sB, 8);

            // ---- PV (swapped): D[d][q]; A = V^T-frag, B = P-frag; + l
            __builtin_amdgcn_s_setprio(1);
            #pragma unroll
            for (int ki = 0; ki < 4; ++ki) {
                const bf16x8 pb = (ki == 0) ? pb0 : (ki == 1) ? pb1 : (ki == 2) ? pb2 : pb3;
                const int bc = ki * 32 + 16 * hl;
                const bf16x8 vfA = *(const bf16x8*)(vtb + sw128(l31, bc));
                const bf16x8 vfB = *(const bf16x8*)(vtb + sw128(32 + l31, bc));
                oA = __builtin_amdgcn_mfma_f32_32x32x16_bf16(vfA, pb, oA, 0, 0, 0);
                oB = __builtin_amdgcn_mfma_f32_32x32x16_bf16(vfB, pb, oB, 0, 0, 0);
                ol = __builtin_amdgcn_mfma_f32_32x32x16_bf16(onesf, pb, ol, 0, 0, 0);
            }
            __builtin_amdgcn_s_setprio(0);
        }
    }

    // ---- finalize: lane (q = l31) holds full l in every ol reg
    const float inv = 1.0f / ol[0];
    const int t = qt * 128 + 32 * w + l31;
    const size_t obase = ((size_t)b * T_SEQ + t) * C_DIM + hed * HD;
    #pragma unroll
    for (int b2 = 0; b2 < 4; ++b2) {
        u16x4 ha, hb;
        #pragma unroll
        for (int r = 0; r < 4; ++r) {
            ha[r] = f2bf(oA[4 * b2 + r] * inv);
            hb[r] = f2bf(oB[4 * b2 + r] * inv);
        }
        const int d0 = 8 * b2 + 4 * hl;
        *(u16x4*)&ABo[obase + d0] = ha;
        *(u16x4*)&ABo[obase + 32 + d0] = hb;
    }
}

// ---------------------------------------------------------------------------
extern "C" void kernel_launch(void* const* d_in, const int* in_sizes, int n_in,
                              void* d_out, int out_size, void* d_ws, size_t ws_size,
                              hipStream_t stream)
{
    const float* x  = (const float*)d_in[0];
    const float* wq = (const float*)d_in[1];
    const float* bq = (const float*)d_in[2];
    const float* wk = (const float*)d_in[3];
    const float* bk = (const float*)d_in[4];
    const float* wv = (const float*)d_in[5];
    const float* bv = (const float*)d_in[6];
    const float* wo = (const float*)d_in[7];
    const float* bo = (const float*)d_in[8];

    ushort_t* Wbase = (ushort_t*)d_ws;
    ushort_t* WQ_H = Wbase;
    ushort_t* WK_H = Wbase + 2 * WE;
    ushort_t* WV_H = Wbase + 4 * WE;
    ushort_t* WO_H = Wbase + 6 * WE;
    ushort_t* WO_L = WO_H + WE;
    ushort_t* X_H  = Wbase + 8 * WE;
    ushort_t* K_B  = X_H + 2 * NE;
    ushort_t* VT_B = K_B + NE;
    ushort_t* Q_B = (ushort_t*)d_out;       // consumed before final GEMM writes
    ushort_t* A_B = X_H;                    // aliases X (dead after QKV GEMM)

    const dim3 blk(256);

    prep<<<3648, blk, 0, stream>>>(x, wq, wk, wv, wo, X_H, Wbase);

    gemm_qkv<<<1152, blk, 0, stream>>>(X_H, WQ_H, WK_H, WV_H,
                                       bq, bk, bv, Q_B, K_B, VT_B);

    attn_fuse11<<<768, blk, 0, stream>>>(Q_B, K_B, VT_B, A_B);

    gemm_out<<<768, blk, 0, stream>>>(A_B, WO_H, WO_L, bo, (float*)d_out);
}

// Round 20
// 146.454 us; speedup vs baseline: 1.0618x; 1.0250x over previous
//
#include <hip/hip_runtime.h>
#include <math.h>

#define NB 4
#define T_SEQ 2048
#define C_DIM 768
#define NH 12
#define HD 64
#define M_TOK (NB * T_SEQ)            // 8192
#define NE ((size_t)M_TOK * C_DIM)    // 6291456
#define WE ((size_t)C_DIM * C_DIM)    // 589824
#define QSCALE 0.18033688011112042f   // 0.125 * log2(e)

typedef short bf16x8 __attribute__((ext_vector_type(8)));
typedef float f32x4 __attribute__((ext_vector_type(4)));
typedef unsigned short u16x4 __attribute__((ext_vector_type(4)));
typedef unsigned short u16x8 __attribute__((ext_vector_type(8)));
typedef unsigned short ushort_t;

__device__ __forceinline__ unsigned short f2bf(float x) {
    unsigned u = __float_as_uint(x);
    u += 0x7FFFu + ((u >> 16) & 1u);
    return (unsigned short)(u >> 16);
}
__device__ __forceinline__ float bf2f(unsigned short h) {
    return __uint_as_float(((unsigned)h) << 16);
}
__device__ __forceinline__ int sw128(int row, int bytecol) {
    return row * 128 + (bytecol ^ ((row & 7) << 4));
}
__device__ __forceinline__ void gload16(const ushort_t* gp, ushort_t* lp) {
    __builtin_amdgcn_global_load_lds(
        (const __attribute__((address_space(1))) unsigned int*)(const void*)gp,
        (__attribute__((address_space(3))) unsigned int*)(void*)lp, 16, 0, 0);
}

// ---------------------------------------------------------------------------
// prep: blocks [0,3072) split X -> single RNE bf16. Blocks [3072,3648):
// transpose-split weights into WT [N][K]; lo half written only for WO
// (the 1-pass QKV GEMM never reads WQ/WK/WV lo).
// ---------------------------------------------------------------------------
__global__ __launch_bounds__(256) void prep(
    const float* __restrict__ X,
    const float* __restrict__ wq, const float* __restrict__ wk,
    const float* __restrict__ wv, const float* __restrict__ wo,
    ushort_t* __restrict__ XH, ushort_t* __restrict__ Wbase)
{
    __shared__ float T[64][65];
    const int tid = threadIdx.x;
    const int bid = blockIdx.x;

    if (bid < 3072) {
        const size_t i = ((size_t)bid * 256 + tid) * 8;
        const float4 f0 = *(const float4*)&X[i];
        const float4 f1 = *(const float4*)&X[i + 4];
        const float xs[8] = {f0.x, f0.y, f0.z, f0.w, f1.x, f1.y, f1.z, f1.w};
        u16x8 h;
        #pragma unroll
        for (int j = 0; j < 8; ++j) h[j] = f2bf(xs[j]);
        *(u16x8*)&XH[i] = h;
        return;
    }

    const int r_ = bid - 3072;
    const int z = r_ / 144;
    const int rem = r_ % 144;
    const int ti = rem / 12, nj = rem % 12;
    const float* W = (z == 0) ? wq : (z == 1) ? wk : (z == 2) ? wv : wo;
    ushort_t* TH = Wbase + (size_t)z * 2 * WE;
    ushort_t* TL = TH + WE;
    {
        const int r = tid >> 2, cq = (tid & 3) * 16;
        #pragma unroll
        for (int j = 0; j < 4; ++j) {
            const float4 f = *(const float4*)&W[(size_t)(ti * 64 + r) * C_DIM + nj * 64 + cq + j * 4];
            T[r][cq + j * 4 + 0] = f.x;
            T[r][cq + j * 4 + 1] = f.y;
            T[r][cq + j * 4 + 2] = f.z;
            T[r][cq + j * 4 + 3] = f.w;
        }
    }
    __syncthreads();
    {
        const int n = tid >> 2, kq = (tid & 3) * 16;
        u16x8 h0, h1, l0, l1;
        #pragma unroll
        for (int j = 0; j < 8; ++j) {
            float v = T[kq + j][n];
            unsigned short hh = f2bf(v);
            h0[j] = hh; l0[j] = f2bf(v - bf2f(hh));
            v = T[kq + 8 + j][n];
            hh = f2bf(v);
            h1[j] = hh; l1[j] = f2bf(v - bf2f(hh));
        }
        const size_t o = (size_t)(nj * 64 + n) * C_DIM + ti * 64 + kq;
        *(u16x8*)&TH[o] = h0; *(u16x8*)&TH[o + 8] = h1;
        if (z == 3) {                      // lo needed only for WO (2-pass out)
            *(u16x8*)&TL[o] = l0; *(u16x8*)&TL[o + 8] = l1;
        }
    }
}

// ---------------------------------------------------------------------------
// Fused QKV GEMM, 1-pass, 128x128 tile, BK=32, double-buffered (r14/r17).
// Q/K: swapped MFMA operands (lane = token, regs = 4 consecutive d) for
// u16x4 d-contiguous stores. V: original orientation ([B,H,D,T] store).
// ---------------------------------------------------------------------------
__global__ __launch_bounds__(256, 4) void gemm_qkv(
    const ushort_t* __restrict__ XH,
    const ushort_t* __restrict__ WQH, const ushort_t* __restrict__ WKH,
    const ushort_t* __restrict__ WVH,
    const float* __restrict__ bq, const float* __restrict__ bk,
    const float* __restrict__ bv,
    ushort_t* __restrict__ Qo, ushort_t* __restrict__ Ko, ushort_t* __restrict__ VTo)
{
    __shared__ ushort_t TA[2][128 * 32];      // 16 KB
    __shared__ ushort_t TB[2][128 * 32];      // 16 KB

    const int tid = threadIdx.x, lane = tid & 63, w = tid >> 6;
    const int l15 = lane & 15, g = lane >> 4;
    const int wr = w >> 1, wc = w & 1;

    int bid = (int)blockIdx.x;
    bid = (bid & 7) * 144 + (bid >> 3);     // 1152 = 8*144, bijective
    const int bm = bid / 18, bn = bid % 18;
    const int wsel = bn / 6, bnw = bn % 6;

    const ushort_t* BH = (wsel == 0) ? WQH : (wsel == 1) ? WKH : WVH;
    const float* bias = (wsel == 0) ? bq : (wsel == 1) ? bk : bv;

    f32x4 acc[4][4];
    #pragma unroll
    for (int m = 0; m < 4; ++m)
        #pragma unroll
        for (int n = 0; n < 4; ++n) acc[m][n] = (f32x4){0.f, 0.f, 0.f, 0.f};

    auto stage = [&](int buf, int k0) {
        #pragma unroll
        for (int p = 0; p < 4; ++p) {
            const int cb = 256 * p + 64 * w;      // wave-uniform chunk base
            const int c  = cb + lane;
            const int row = (c & 511) >> 2;
            const int slot = (c & 3) ^ ((row >> 1) & 3);
            if (cb < 512)
                gload16(XH + ((size_t)bm * 128 + row) * C_DIM + k0 + slot * 8,
                        &TA[buf][(cb & 511) * 8]);
            else
                gload16(BH + ((size_t)bnw * 128 + row) * C_DIM + k0 + slot * 8,
                        &TB[buf][(cb & 511) * 8]);
        }
    };

    stage(0, 0);
    int cur = 0;
    if (wsel < 2) {
        for (int k0 = 0; k0 < C_DIM; k0 += 32) {
            __syncthreads();
            if (k0 + 32 < C_DIM) stage(cur ^ 1, k0 + 32);
            bf16x8 ah[4], bh_[4];
            #pragma unroll
            for (int m = 0; m < 4; ++m) {
                const int r = 64 * wr + 16 * m + l15;
                const int off = r * 64 + ((g ^ ((r >> 1) & 3)) << 4);
                ah[m] = *(const bf16x8*)((const char*)TA[cur] + off);
            }
            #pragma unroll
            for (int n = 0; n < 4; ++n) {
                const int r = 64 * wc + 16 * n + l15;
                const int off = r * 64 + ((g ^ ((r >> 1) & 3)) << 4);
                bh_[n] = *(const bf16x8*)((const char*)TB[cur] + off);
            }
            #pragma unroll
            for (int m = 0; m < 4; ++m)
                #pragma unroll
                for (int n = 0; n < 4; ++n)
                    acc[m][n] = __builtin_amdgcn_mfma_f32_16x16x32_bf16(bh_[n], ah[m], acc[m][n], 0, 0, 0);
            cur ^= 1;
        }
        const float oscale = (wsel == 0) ? QSCALE : 1.0f;
        ushort_t* OH = (wsel == 0) ? Qo : Ko;
        #pragma unroll
        for (int n = 0; n < 4; ++n) {
            const int colw0 = bnw * 128 + 64 * wc + 16 * n + 4 * g;
            const float4 bv4 = *(const float4*)&bias[colw0];
            const float bvr[4] = {bv4.x, bv4.y, bv4.z, bv4.w};
            const int h = colw0 >> 6, d0 = colw0 & 63;
            #pragma unroll
            for (int m = 0; m < 4; ++m) {
                const int t = bm * 128 + 64 * wr + 16 * m + l15;
                const int b = t >> 11, tt = t & (T_SEQ - 1);
                u16x4 ph;
                #pragma unroll
                for (int r = 0; r < 4; ++r)
                    ph[r] = f2bf((acc[m][n][r] + bvr[r]) * oscale);
                *(u16x4*)&OH[(((size_t)b * NH + h) * T_SEQ + tt) * HD + d0] = ph;
            }
        }
    } else {
        for (int k0 = 0; k0 < C_DIM; k0 += 32) {
            __syncthreads();
            if (k0 + 32 < C_DIM) stage(cur ^ 1, k0 + 32);
            bf16x8 ah[4], bh_[4];
            #pragma unroll
            for (int m = 0; m < 4; ++m) {
                const int r = 64 * wr + 16 * m + l15;
                const int off = r * 64 + ((g ^ ((r >> 1) & 3)) << 4);
                ah[m] = *(const bf16x8*)((const char*)TA[cur] + off);
            }
            #pragma unroll
            for (int n = 0; n < 4; ++n) {
                const int r = 64 * wc + 16 * n + l15;
                const int off = r * 64 + ((g ^ ((r >> 1) & 3)) << 4);
                bh_[n] = *(const bf16x8*)((const char*)TB[cur] + off);
            }
            #pragma unroll
            for (int m = 0; m < 4; ++m)
                #pragma unroll
                for (int n = 0; n < 4; ++n)
                    acc[m][n] = __builtin_amdgcn_mfma_f32_16x16x32_bf16(ah[m], bh_[n], acc[m][n], 0, 0, 0);
            cur ^= 1;
        }
        #pragma unroll
        for (int n = 0; n < 4; ++n) {
            const int colw = bnw * 128 + 64 * wc + 16 * n + l15;
            const float bv_ = bias[colw];
            const int h = colw >> 6, d = colw & 63;
            #pragma unroll
            for (int m = 0; m < 4; ++m) {
                const int row0 = bm * 128 + 64 * wr + 16 * m + 4 * g;
                u16x4 ph;
                #pragma unroll
                for (int r = 0; r < 4; ++r) ph[r] = f2bf(acc[m][n][r] + bv_);
                const int b = row0 >> 11, t0 = row0 & (T_SEQ - 1);
                *(u16x4*)&VTo[(((size_t)b * NH + h) * HD + d) * T_SEQ + t0] = ph;
            }
        }
    }
}

// ---------------------------------------------------------------------------
// Output GEMM, 2-pass (a*wh + a*wl), 128x64 tile, double-buffered (r17):
// lane = col orientation -> 64B contiguous row-chunk stores.
// ---------------------------------------------------------------------------
__global__ __launch_bounds__(256, 4) void gemm_out(
    const ushort_t* __restrict__ AB,
    const ushort_t* __restrict__ BH, const ushort_t* __restrict__ BL,
    const float* __restrict__ bias, float* __restrict__ OutF)
{
    __shared__ ushort_t TA[2][128 * 32];      // 16 KB
    __shared__ ushort_t TB[2][2][64 * 32];    // 16 KB

    const int tid = threadIdx.x, lane = tid & 63, w = tid >> 6;
    const int l15 = lane & 15, g = lane >> 4;
    const int wr = w >> 1, wc = w & 1;

    int bid = (int)blockIdx.x;
    bid = (bid & 7) * 96 + (bid >> 3);     // 768 = 8*96
    const int bm = bid / 12, bn = bid % 12;

    f32x4 acc[4][2];
    #pragma unroll
    for (int m = 0; m < 4; ++m)
        #pragma unroll
        for (int n = 0; n < 2; ++n) acc[m][n] = (f32x4){0.f, 0.f, 0.f, 0.f};

    auto stage = [&](int buf, int k0) {
        #pragma unroll
        for (int p = 0; p < 4; ++p) {
            const int c = w + 4 * p;       // 0..15
            if (c < 8) {
                const int row = c * 16 + (lane >> 2);
                const int slot = (lane & 3) ^ ((row >> 1) & 3);
                gload16(AB + ((size_t)bm * 128 + row) * C_DIM + k0 + slot * 8,
                        &TA[buf][c * 512]);
            } else {
                const int t_ = (c - 8) >> 2;
                const int cc = c & 3;
                const int row = cc * 16 + (lane >> 2);
                const int slot = (lane & 3) ^ ((row >> 1) & 3);
                const ushort_t* src = (t_ ? BL : BH) + ((size_t)bn * 64 + row) * C_DIM + k0 + slot * 8;
                gload16(src, &TB[buf][t_][cc * 512]);
            }
        }
    };

    stage(0, 0);
    int cur = 0;
    for (int k0 = 0; k0 < C_DIM; k0 += 32) {
        __syncthreads();
        if (k0 + 32 < C_DIM) stage(cur ^ 1, k0 + 32);

        bf16x8 a_[4], bh_[2], bl_[2];
        #pragma unroll
        for (int m = 0; m < 4; ++m) {
            const int r = 64 * wr + 16 * m + l15;
            const int off = r * 64 + ((g ^ ((r >> 1) & 3)) << 4);
            a_[m] = *(const bf16x8*)((const char*)TA[cur] + off);
        }
        #pragma unroll
        for (int n = 0; n < 2; ++n) {
            const int r = 32 * wc + 16 * n + l15;
            const int off = r * 64 + ((g ^ ((r >> 1) & 3)) << 4);
            bh_[n] = *(const bf16x8*)((const char*)TB[cur][0] + off);
            bl_[n] = *(const bf16x8*)((const char*)TB[cur][1] + off);
        }
        #pragma unroll
        for (int m = 0; m < 4; ++m)
            #pragma unroll
            for (int n = 0; n < 2; ++n) {
                acc[m][n] = __builtin_amdgcn_mfma_f32_16x16x32_bf16(a_[m], bh_[n], acc[m][n], 0, 0, 0);
                acc[m][n] = __builtin_amdgcn_mfma_f32_16x16x32_bf16(a_[m], bl_[n], acc[m][n], 0, 0, 0);
            }
        cur ^= 1;
    }

    #pragma unroll
    for (int n = 0; n < 2; ++n) {
        const int col = bn * 64 + 32 * wc + 16 * n + l15;
        const float bv = bias[col];
        #pragma unroll
        for (int m = 0; m < 4; ++m) {
            const int row0 = bm * 128 + 64 * wr + 16 * m + 4 * g;
            #pragma unroll
            for (int r = 0; r < 4; ++r)
                OutF[(size_t)(row0 + r) * C_DIM + col] = acc[m][n][r] + bv;
        }
    }
}

// ---------------------------------------------------------------------------
// Flash attention v9b (r17 best): 4 waves x 32 q (reg-blocked, 16x16 MFMA),
// KVBLK=128 per barrier-pair, swapped QK^T, no-max softmax (exp2, truncated
// bf16 P via v_perm), l on the matrix pipe (ones-MFMA), hoisted setprio.
// ---------------------------------------------------------------------------
__global__ __launch_bounds__(256, 3) void attn_fuse9(
    const ushort_t* __restrict__ QB, const ushort_t* __restrict__ KB,
    const ushort_t* __restrict__ VTB, ushort_t* __restrict__ ABo)
{
    __shared__ ushort_t Ks[2][64 * 64];   // [half][key][d] swizzled, 16 KB
    __shared__ ushort_t Vt[2][64 * 64];   // [half][d][key] swizzled, 16 KB
    __shared__ ushort_t Pm[4][32 * 64];   // 16 KB

    const int tid = threadIdx.x, lane = tid & 63, w = tid >> 6;
    const int l15 = lane & 15, g = lane >> 4;

    int bid = (int)blockIdx.x;
    bid = (bid & 7) * 96 + (bid >> 3);    // 768 = 8*96, bijective
    const int bh = bid >> 4, qt = bid & 15;
    const int b = bh / NH, h = bh % NH;

    bf16x8 qf0[2], qf1[2];
    #pragma unroll
    for (int kc = 0; kc < 2; ++kc) {
        const size_t base = ((size_t)bh * T_SEQ + qt * 128 + 32 * w + l15) * HD + kc * 32 + g * 8;
        qf0[kc] = *(const bf16x8*)&QB[base];
        qf1[kc] = *(const bf16x8*)&QB[base + (size_t)16 * HD];
    }

    bf16x8 onesf;
    #pragma unroll
    for (int j = 0; j < 8; ++j) onesf[j] = (short)0x3F80;

    f32x4 o0[4], o1[4];
    #pragma unroll
    for (int nd = 0; nd < 4; ++nd) {
        o0[nd] = (f32x4){0.f, 0.f, 0.f, 0.f};
        o1[nd] = (f32x4){0.f, 0.f, 0.f, 0.f};
    }
    f32x4 ol0 = (f32x4){0.f, 0.f, 0.f, 0.f};
    f32x4 ol1 = (f32x4){0.f, 0.f, 0.f, 0.f};

    const ushort_t* kb = KB + (size_t)bh * T_SEQ * HD;
    const ushort_t* vb = VTB + (size_t)bh * HD * T_SEQ;
    const int swz = (l15 & 7) << 4;

    const ushort_t *gK0, *gK1, *gV0, *gV1;
    {
        const int c0 = w * 64 + lane;
        const int r0 = c0 >> 3;
        const int cb0 = ((c0 & 7) * 16) ^ ((r0 & 7) << 4);
        gK0 = kb + (size_t)r0 * HD + (cb0 >> 1);
        gV0 = vb + (size_t)r0 * T_SEQ + (cb0 >> 1);
        const int c1 = c0 + 256;
        const int r1 = c1 >> 3;
        const int cb1 = ((c1 & 7) * 16) ^ ((r1 & 7) << 4);
        gK1 = kb + (size_t)r1 * HD + (cb1 >> 1);
        gV1 = vb + (size_t)r1 * T_SEQ + (cb1 >> 1);
    }
    ushort_t* dK0 = &Ks[0][w * 512];
    ushort_t* dK1 = &Ks[0][2048 + w * 512];
    ushort_t* dV0 = &Vt[0][w * 512];
    ushort_t* dV1 = &Vt[0][2048 + w * 512];

    for (int kt = 0; kt < T_SEQ; kt += 128) {
        __syncthreads();                 // previous tile's reads complete
        gload16(gK0, dK0);
        gload16(gK1, dK1);
        gload16(gV0, dV0);
        gload16(gV1, dV1);
        gload16(gK0 + (size_t)64 * HD, dK0 + 4096);
        gload16(gK1 + (size_t)64 * HD, dK1 + 4096);
        gload16(gV0 + 64, dV0 + 4096);
        gload16(gV1 + 64, dV1 + 4096);
        gK0 += (size_t)128 * HD; gK1 += (size_t)128 * HD;
        gV0 += 128; gV1 += 128;
        __syncthreads();                 // 128-key tile staged

        #pragma unroll
        for (int half = 0; half < 2; ++half) {
            const char* ksb = (const char*)Ks[half];
            const char* vtb = (const char*)Vt[half];

            // ---- QK^T (swapped): each kf feeds both q-halves
            f32x4 s0[4], s1[4];
            #pragma unroll
            for (int nb = 0; nb < 4; ++nb) {
                s0[nb] = (f32x4){0.f, 0.f, 0.f, 0.f};
                s1[nb] = (f32x4){0.f, 0.f, 0.f, 0.f};
            }
            __builtin_amdgcn_s_setprio(1);
            #pragma unroll
            for (int kc = 0; kc < 2; ++kc)
                #pragma unroll
                for (int nb = 0; nb < 4; ++nb) {
                    const bf16x8 kf = *(const bf16x8*)(ksb + sw128(16 * nb + l15, kc * 64 + g * 16));
                    s0[nb] = __builtin_amdgcn_mfma_f32_16x16x32_bf16(kf, qf0[kc], s0[nb], 0, 0, 0);
                    s1[nb] = __builtin_amdgcn_mfma_f32_16x16x32_bf16(kf, qf1[kc], s1[nb], 0, 0, 0);
                }
            __builtin_amdgcn_s_setprio(0);

            // ---- no-max softmax: p = exp2(s) (raw v_exp_f32); truncate-pack
            #pragma unroll
            for (int nb = 0; nb < 4; ++nb) {
                const float a0 = __builtin_amdgcn_exp2f(s0[nb][0]);
                const float a1 = __builtin_amdgcn_exp2f(s0[nb][1]);
                const float a2 = __builtin_amdgcn_exp2f(s0[nb][2]);
                const float a3 = __builtin_amdgcn_exp2f(s0[nb][3]);
                const unsigned dwa0 = __builtin_amdgcn_perm(
                    __float_as_uint(a1), __float_as_uint(a0), 0x07060302u);
                const unsigned dwa1 = __builtin_amdgcn_perm(
                    __float_as_uint(a3), __float_as_uint(a2), 0x07060302u);
                *(uint2*)((char*)Pm[w] + l15 * 128 + ((32 * nb + 8 * g) ^ swz)) =
                    make_uint2(dwa0, dwa1);

                const float b0 = __builtin_amdgcn_exp2f(s1[nb][0]);
                const float b1 = __builtin_amdgcn_exp2f(s1[nb][1]);
                const float b2 = __builtin_amdgcn_exp2f(s1[nb][2]);
                const float b3 = __builtin_amdgcn_exp2f(s1[nb][3]);
                const unsigned dwb0 = __builtin_amdgcn_perm(
                    __float_as_uint(b1), __float_as_uint(b0), 0x07060302u);
                const unsigned dwb1 = __builtin_amdgcn_perm(
                    __float_as_uint(b3), __float_as_uint(b2), 0x07060302u);
                *(uint2*)((char*)Pm[w] + (16 + l15) * 128 + ((32 * nb + 8 * g) ^ swz)) =
                    make_uint2(dwb0, dwb1);
            }

            // ---- PV (swapped) + l via ones-MFMA; single setprio window
            __builtin_amdgcn_s_setprio(1);
            #pragma unroll
            for (int kc2 = 0; kc2 < 2; ++kc2) {
                const bf16x8 pb0 = *(const bf16x8*)((const char*)Pm[w] + l15 * 128 + ((kc2 * 64 + g * 16) ^ swz));
                const bf16x8 pb1 = *(const bf16x8*)((const char*)Pm[w] + (16 + l15) * 128 + ((kc2 * 64 + g * 16) ^ swz));
                #pragma unroll
                for (int nd = 0; nd < 4; ++nd) {
                    const bf16x8 vf = *(const bf16x8*)(vtb + sw128(16 * nd + l15, kc2 * 64 + g * 16));
                    o0[nd] = __builtin_amdgcn_mfma_f32_16x16x32_bf16(vf, pb0, o0[nd], 0, 0, 0);
                    o1[nd] = __builtin_amdgcn_mfma_f32_16x16x32_bf16(vf, pb1, o1[nd], 0, 0, 0);
                }
                ol0 = __builtin_amdgcn_mfma_f32_16x16x32_bf16(onesf, pb0, ol0, 0, 0, 0);
                ol1 = __builtin_amdgcn_mfma_f32_16x16x32_bf16(onesf, pb1, ol1, 0, 0, 0);
            }
            __builtin_amdgcn_s_setprio(0);
        }
    }

    const float inv0 = 1.0f / ol0[0];
    const float inv1 = 1.0f / ol1[0];
    const int t0 = qt * 128 + 32 * w + l15;
    #pragma unroll
    for (int nd = 0; nd < 4; ++nd) {
        u16x4 h0_, h1_;
        #pragma unroll
        for (int r = 0; r < 4; ++r) {
            h0_[r] = f2bf(o0[nd][r] * inv0);
            h1_[r] = f2bf(o1[nd][r] * inv1);
        }
        const size_t col = h * HD + 16 * nd + 4 * g;
        *(u16x4*)&ABo[((size_t)b * T_SEQ + t0) * C_DIM + col] = h0_;
        *(u16x4*)&ABo[((size_t)b * T_SEQ + t0 + 16) * C_DIM + col] = h1_;
    }
}

// ---------------------------------------------------------------------------
extern "C" void kernel_launch(void* const* d_in, const int* in_sizes, int n_in,
                              void* d_out, int out_size, void* d_ws, size_t ws_size,
                              hipStream_t stream)
{
    const float* x  = (const float*)d_in[0];
    const float* wq = (const float*)d_in[1];
    const float* bq = (const float*)d_in[2];
    const float* wk = (const float*)d_in[3];
    const float* bk = (const float*)d_in[4];
    const float* wv = (const float*)d_in[5];
    const float* bv = (const float*)d_in[6];
    const float* wo = (const float*)d_in[7];
    const float* bo = (const float*)d_in[8];

    ushort_t* Wbase = (ushort_t*)d_ws;
    ushort_t* WQ_H = Wbase;
    ushort_t* WK_H = Wbase + 2 * WE;
    ushort_t* WV_H = Wbase + 4 * WE;
    ushort_t* WO_H = Wbase + 6 * WE;
    ushort_t* WO_L = WO_H + WE;
    ushort_t* X_H  = Wbase + 8 * WE;
    ushort_t* K_B  = X_H + 2 * NE;
    ushort_t* VT_B = K_B + NE;
    ushort_t* Q_B = (ushort_t*)d_out;       // consumed before final GEMM writes
    ushort_t* A_B = X_H;                    // aliases X (dead after QKV GEMM)

    const dim3 blk(256);

    prep<<<3648, blk, 0, stream>>>(x, wq, wk, wv, wo, X_H, Wbase);

    gemm_qkv<<<1152, blk, 0, stream>>>(X_H, WQ_H, WK_H, WV_H,
                                       bq, bk, bv, Q_B, K_B, VT_B);

    attn_fuse9<<<768, blk, 0, stream>>>(Q_B, K_B, VT_B, A_B);

    gemm_out<<<768, blk, 0, stream>>>(A_B, WO_H, WO_L, bo, (float*)d_out);
}